// Round 1
// baseline (348.540 us; speedup 1.0000x reference)
//
#include <hip/hip_runtime.h>
#include <hip/hip_bf16.h>

#define BATCH 64
#define CCH 128
#define SEQ 1024
#define NG 32
#define EPSV 1e-6f
#define SCALEV 0.044194173824159216f

typedef short v8s __attribute__((ext_vector_type(8)));
typedef float v4f __attribute__((ext_vector_type(4)));

__device__ __forceinline__ unsigned short f2bf(float f) {
    __hip_bfloat16 h = __float2bfloat16(f);
    return *reinterpret_cast<unsigned short*>(&h);
}

// ---------------- weights fp32 -> bf16 ----------------
__global__ void prep_weights(const float* wq, const float* wk, const float* wv,
                             const float* wo, unsigned short* wbf) {
    int i = blockIdx.x * 256 + threadIdx.x;     // 0..65535
    const float* srcs[4] = {wq, wk, wv, wo};
    int m = i >> 14;
    int j = i & 16383;
    wbf[i] = f2bf(srcs[m][j]);
}

// ---------------- GroupNorm stats: one block per (b,g) ----------------
__global__ void gn_stats(const float* __restrict__ x, float* meanr, float* rstdr) {
    int bg = blockIdx.x;                         // b*NG + g
    const float* p = x + (size_t)bg * (4 * SEQ); // group = 4 contiguous channels
    int tid = threadIdx.x;
    float s1 = 0.f, s2 = 0.f;
    for (int i = tid; i < 4 * SEQ; i += 256) {
        float v = p[i];
        s1 += v; s2 += v * v;
    }
    #pragma unroll
    for (int off = 32; off; off >>= 1) {
        s1 += __shfl_down(s1, off);
        s2 += __shfl_down(s2, off);
    }
    __shared__ float a1[4], a2[4];
    int w = tid >> 6, l = tid & 63;
    if (l == 0) { a1[w] = s1; a2[w] = s2; }
    __syncthreads();
    if (tid == 0) {
        float t1 = a1[0] + a1[1] + a1[2] + a1[3];
        float t2 = a2[0] + a2[1] + a2[2] + a2[3];
        float mean = t1 * (1.0f / (4 * SEQ));
        float var  = t2 * (1.0f / (4 * SEQ)) - mean * mean;
        meanr[bg] = mean;
        rstdr[bg] = rsqrtf(var + EPSV);
    }
}

// ---------------- fused GroupNorm-apply + QKV projection ----------------
// grid: 8 s-tiles x 64 batches; block 256 (4 waves); tile 128 rows x 128 cols
__global__ __launch_bounds__(256) void qkv_kernel(
    const float* __restrict__ x, const float* __restrict__ gn_w,
    const float* __restrict__ gn_b, const float* __restrict__ meanr,
    const float* __restrict__ rstdr, const unsigned short* __restrict__ wbf,
    const float* __restrict__ bq, const float* __restrict__ bk,
    const float* __restrict__ bv,
    unsigned short* Q, unsigned short* K, unsigned short* Vt)
{
    __shared__ unsigned short tls[128 * 136];    // t[s][c], pitch 136 (2-way-free)
    int bx = blockIdx.x & 7;
    int b  = blockIdx.x >> 3;
    int s0 = bx * 128;
    int tid = threadIdx.x;
    const float* xb = x + (size_t)b * CCH * SEQ;

    // load x tile, normalize, write t[s][c] bf16 to LDS
    for (int rep = 0; rep < 64; rep++) {
        int idx = rep * 256 + tid;
        int c = idx >> 7, s = idx & 127;
        float v = xb[c * SEQ + s0 + s];
        int g = c >> 2;
        float t = (v - meanr[b * NG + g]) * rstdr[b * NG + g] * gn_w[c] + gn_b[c];
        tls[s * 136 + c] = f2bf(t);
    }
    __syncthreads();

    int w = tid >> 6, lane = tid & 63;
    int m = lane & 15, quad = lane >> 4;

    // A-fragments: wave owns 32 rows (2 stripes of 16)
    v8s a[2][4];
    #pragma unroll
    for (int st = 0; st < 2; st++)
        #pragma unroll
        for (int ch = 0; ch < 4; ch++)
            a[st][ch] = *(const v8s*)&tls[(w * 32 + st * 16 + m) * 136 + ch * 32 + quad * 8];
    __syncthreads();   // everyone has frags; tls reusable for Vt transpose

    #pragma unroll
    for (int o = 0; o < 3; o++) {
        const unsigned short* wmat = wbf + o * 16384;
        const float* bias = (o == 0) ? bq : (o == 1) ? bk : bv;
        #pragma unroll
        for (int ct = 0; ct < 8; ct++) {
            v4f acc0 = {0,0,0,0}, acc1 = {0,0,0,0};
            #pragma unroll
            for (int ch = 0; ch < 4; ch++) {
                v8s bfr = *(const v8s*)&wmat[(ct * 16 + m) * 128 + ch * 32 + quad * 8];
                acc0 = __builtin_amdgcn_mfma_f32_16x16x32_bf16(a[0][ch], bfr, acc0, 0, 0, 0);
                acc1 = __builtin_amdgcn_mfma_f32_16x16x32_bf16(a[1][ch], bfr, acc1, 0, 0, 0);
            }
            int col = ct * 16 + m;
            float bcol = bias[col];
            if (o < 2) {
                unsigned short* dst = (o == 0 ? Q : K) + (size_t)b * SEQ * CCH;
                #pragma unroll
                for (int r = 0; r < 4; r++) {
                    int row0 = w * 32 + quad * 4 + r;
                    dst[(size_t)(s0 + row0) * 128 + col]      = f2bf(acc0[r] + bcol);
                    dst[(size_t)(s0 + row0 + 16) * 128 + col] = f2bf(acc1[r] + bcol);
                }
            } else {
                // V: transpose into LDS as vt[c][s_local]
                #pragma unroll
                for (int r = 0; r < 4; r++) {
                    int row0 = w * 32 + quad * 4 + r;
                    tls[col * 136 + row0]      = f2bf(acc0[r] + bcol);
                    tls[col * 136 + row0 + 16] = f2bf(acc1[r] + bcol);
                }
            }
        }
    }
    __syncthreads();
    // coalesced Vt store: Vt[b][c][s]
    unsigned short* vdst = Vt + (size_t)b * CCH * SEQ;
    for (int rep = 0; rep < 64; rep++) {
        int idx = rep * 256 + tid;
        int c = idx >> 7, s = idx & 127;
        vdst[c * SEQ + s0 + s] = tls[c * 136 + s];
    }
}

// ---------------- attention: 32 Q-rows per block, full score strip in LDS ----
// grid: 32 s-tiles x 64 batches; block 256 (4 waves)
__global__ __launch_bounds__(256) void attn_kernel(
    const unsigned short* __restrict__ Q, const unsigned short* __restrict__ K,
    const unsigned short* __restrict__ Vt, unsigned short* O)
{
    __shared__ float smem[32 * 1036];            // score strip, pitch 1036
    __shared__ float rowsum[32];
    int bx = blockIdx.x & 31;
    int b  = blockIdx.x >> 5;
    int s0 = bx * 32;
    int tid = threadIdx.x;
    int w = tid >> 6, lane = tid & 63;
    int m = lane & 15, quad = lane >> 4;
    const unsigned short* Qb = Q + (size_t)b * SEQ * CCH;
    const unsigned short* Kb = K + (size_t)b * SEQ * CCH;
    const unsigned short* Vb = Vt + (size_t)b * CCH * SEQ;

    // Q A-fragments for this block's 32 rows
    v8s a[2][4];
    #pragma unroll
    for (int st = 0; st < 2; st++)
        #pragma unroll
        for (int ch = 0; ch < 4; ch++)
            a[st][ch] = *(const v8s*)&Qb[(size_t)(s0 + st * 16 + m) * 128 + ch * 32 + quad * 8];

    // scores: wave w covers keys [w*256, w*256+256)
    for (int ct = 0; ct < 16; ct++) {
        int t0 = w * 256 + ct * 16;
        v8s bfr[4];
        #pragma unroll
        for (int ch = 0; ch < 4; ch++)
            bfr[ch] = *(const v8s*)&Kb[(size_t)(t0 + m) * 128 + ch * 32 + quad * 8];
        #pragma unroll
        for (int st = 0; st < 2; st++) {
            v4f acc = {0,0,0,0};
            #pragma unroll
            for (int ch = 0; ch < 4; ch++)
                acc = __builtin_amdgcn_mfma_f32_16x16x32_bf16(a[st][ch], bfr[ch], acc, 0, 0, 0);
            #pragma unroll
            for (int r = 0; r < 4; r++)
                smem[(st * 16 + quad * 4 + r) * 1036 + t0 + m] = acc[r] * SCALEV;
        }
    }
    __syncthreads();

    // softmax: wave w handles rows w*8..w*8+7; P written bf16 in place
    for (int r8 = 0; r8 < 8; r8++) {
        int row = w * 8 + r8;
        float* srow = smem + row * 1036;
        unsigned short* prow = (unsigned short*)srow;
        float mx = -1e30f;
        #pragma unroll
        for (int i = 0; i < 16; i++) mx = fmaxf(mx, srow[i * 64 + lane]);
        #pragma unroll
        for (int off = 32; off; off >>= 1) mx = fmaxf(mx, __shfl_xor(mx, off));
        float sum = 0.f;
        for (int i = 0; i < 16; i++) {
            float e = __expf(srow[i * 64 + lane] - mx);   // read-before-write, safe
            sum += e;
            prow[i * 64 + lane] = f2bf(e);
        }
        #pragma unroll
        for (int off = 32; off; off >>= 1) sum += __shfl_xor(sum, off);
        if (lane == 0) rowsum[row] = sum;
    }
    __syncthreads();

    // PV: wave w computes cols [w*32, w*32+32), all 32 rows
    const unsigned short* psm = (const unsigned short*)smem;  // pitch 2072 ushorts
    v4f oacc[2][2] = {{{0,0,0,0},{0,0,0,0}},{{0,0,0,0},{0,0,0,0}}};
    for (int ch = 0; ch < 32; ch++) {
        v8s pa[2], vbr[2];
        #pragma unroll
        for (int st = 0; st < 2; st++)
            pa[st] = *(const v8s*)&psm[(st * 16 + m) * 2072 + ch * 32 + quad * 8];
        #pragma unroll
        for (int cb = 0; cb < 2; cb++)
            vbr[cb] = *(const v8s*)&Vb[(size_t)(w * 32 + cb * 16 + m) * SEQ + ch * 32 + quad * 8];
        #pragma unroll
        for (int st = 0; st < 2; st++)
            #pragma unroll
            for (int cb = 0; cb < 2; cb++)
                oacc[st][cb] = __builtin_amdgcn_mfma_f32_16x16x32_bf16(pa[st], vbr[cb], oacc[st][cb], 0, 0, 0);
    }
    unsigned short* Ob = O + (size_t)b * SEQ * CCH;
    #pragma unroll
    for (int st = 0; st < 2; st++)
        #pragma unroll
        for (int cb = 0; cb < 2; cb++)
            #pragma unroll
            for (int r = 0; r < 4; r++) {
                int row = st * 16 + quad * 4 + r;
                int col = w * 32 + cb * 16 + m;
                Ob[(size_t)(s0 + row) * 128 + col] = f2bf(oacc[st][cb][r] / rowsum[row]);
            }
}

// ---------------- out projection + residual + transpose to [b][c][s] --------
__global__ __launch_bounds__(256) void outproj_kernel(
    const unsigned short* __restrict__ O, const unsigned short* __restrict__ wbo,
    const float* __restrict__ bo, const float* __restrict__ x, float* out)
{
    __shared__ float tr[128 * 129];
    int bx = blockIdx.x & 7;
    int b  = blockIdx.x >> 3;
    int s0 = bx * 128;
    int tid = threadIdx.x;
    int w = tid >> 6, lane = tid & 63;
    int m = lane & 15, quad = lane >> 4;
    const unsigned short* Ob = O + (size_t)b * SEQ * CCH;

    v8s a[2][4];
    #pragma unroll
    for (int st = 0; st < 2; st++)
        #pragma unroll
        for (int ch = 0; ch < 4; ch++)
            a[st][ch] = *(const v8s*)&Ob[(size_t)(s0 + w * 32 + st * 16 + m) * 128 + ch * 32 + quad * 8];

    #pragma unroll
    for (int ct = 0; ct < 8; ct++) {
        v4f acc0 = {0,0,0,0}, acc1 = {0,0,0,0};
        #pragma unroll
        for (int ch = 0; ch < 4; ch++) {
            v8s bfr = *(const v8s*)&wbo[(ct * 16 + m) * 128 + ch * 32 + quad * 8];
            acc0 = __builtin_amdgcn_mfma_f32_16x16x32_bf16(a[0][ch], bfr, acc0, 0, 0, 0);
            acc1 = __builtin_amdgcn_mfma_f32_16x16x32_bf16(a[1][ch], bfr, acc1, 0, 0, 0);
        }
        int col = ct * 16 + m;
        float bcol = bo[col];
        #pragma unroll
        for (int r = 0; r < 4; r++) {
            int srow0 = w * 32 + quad * 4 + r;
            tr[col * 129 + srow0]      = acc0[r] + bcol;
            tr[col * 129 + srow0 + 16] = acc1[r] + bcol;
        }
    }
    __syncthreads();
    const float* xb = x + (size_t)b * CCH * SEQ;
    float* ob = out + (size_t)b * CCH * SEQ;
    for (int rep = 0; rep < 64; rep++) {
        int idx = rep * 256 + tid;
        int c = idx >> 7, s = idx & 127;
        ob[c * SEQ + s0 + s] = tr[c * 129 + s] + xb[c * SEQ + s0 + s];
    }
}

extern "C" void kernel_launch(void* const* d_in, const int* in_sizes, int n_in,
                              void* d_out, int out_size, void* d_ws, size_t ws_size,
                              hipStream_t stream) {
    const float* x    = (const float*)d_in[0];
    const float* gn_w = (const float*)d_in[1];
    const float* gn_b = (const float*)d_in[2];
    const float* wq   = (const float*)d_in[3];
    const float* bq   = (const float*)d_in[4];
    const float* wk   = (const float*)d_in[5];
    const float* bk   = (const float*)d_in[6];
    const float* wv   = (const float*)d_in[7];
    const float* bv   = (const float*)d_in[8];
    const float* wo   = (const float*)d_in[9];
    const float* bo   = (const float*)d_in[10];
    float* out = (float*)d_out;

    char* ws = (char*)d_ws;
    // layout: wbf 128KB | mean 8KB | rstd 8KB | pad | Q 16MB | K 16MB | Vt 16MB
    unsigned short* wbf   = (unsigned short*)ws;
    float* meanr          = (float*)(ws + 131072);
    float* rstdr          = (float*)(ws + 139264);
    unsigned short* Qbuf  = (unsigned short*)(ws + 147456);
    unsigned short* Kbuf  = (unsigned short*)(ws + 147456 + 16777216ull);
    unsigned short* Vtbuf = (unsigned short*)(ws + 147456 + 2ull * 16777216ull);
    unsigned short* Obuf  = Qbuf;  // safe alias: attn block reads only its own
                                   // 32 Q rows (at block start) and writes the
                                   // same 32 O rows (at block end)

    prep_weights<<<256, 256, 0, stream>>>(wq, wk, wv, wo, wbf);
    gn_stats<<<BATCH * NG, 256, 0, stream>>>(x, meanr, rstdr);
    qkv_kernel<<<BATCH * 8, 256, 0, stream>>>(x, gn_w, gn_b, meanr, rstdr, wbf,
                                              bq, bk, bv, Qbuf, Kbuf, Vtbuf);
    attn_kernel<<<BATCH * 32, 256, 0, stream>>>(Qbuf, Kbuf, Vtbuf, Obuf);
    outproj_kernel<<<BATCH * 8, 256, 0, stream>>>(Obuf, wbf + 3 * 16384, bo, x, out);
}